// Round 9
// baseline (1747.003 us; speedup 1.0000x reference)
//
#include <hip/hip_runtime.h>
#include <hip/hip_cooperative_groups.h>

namespace cg = cooperative_groups;

#define D 64
constexpr int U_ = 50000, B_ = 20000, I_ = 40000;
constexpr int RPB  = 128;        // rows per bucket
constexpr int MAXB = 708;        // max buckets (n<=90000 -> 704)
constexpr int PTILE = 8192;      // edges per partition block

// Side-dependent bucket capacities (exact counts + x8 row padding + >=9 sigma).
constexpr int NBU = 390;
constexpr int CAPU_UI = 3584, CAPB_UI = 4352;   // deg 20 / 25 per row
constexpr int CAPA    = 2560;                   // agg: unpadded rows, deg 15
constexpr int CAPU_UB = 2432, CAPB_UB = 4864;   // deg 12 / 30
constexpr int CAPU_UX = 2944, CAPB_UX = 6272;   // deg 16 / 40

__device__ __forceinline__ int g_nbU(int seg) { return seg == 1 ? 0 : NBU; }
__device__ __forceinline__ int g_capU(int seg) {
    switch (seg) { case 0: return CAPU_UI; case 1: return CAPA;
                   case 2: return CAPU_UB; default: return CAPU_UX; }
}
__device__ __forceinline__ int g_capB(int seg) {
    switch (seg) { case 0: return CAPB_UI; case 1: return CAPA;
                   case 2: return CAPB_UB; default: return CAPB_UX; }
}
__device__ __forceinline__ int bbase(int seg, int b) {   // bucket region start
    int nbU = g_nbU(seg);
    return (b <= nbU) ? b * g_capU(seg)
                      : nbU * g_capU(seg) + (b - nbU) * g_capB(seg);
}

__device__ __forceinline__ unsigned short f2bf(float f) {   // RTN-even
    unsigned int u = __float_as_uint(f);
    return (unsigned short)((u + 0x7FFFu + ((u >> 16) & 1u)) >> 16);
}

struct BuildP {                   // all-4-graph fused build parameters
    const int *r0, *r1, *r2, *r3; // row arrays
    int nnz0, nnz1, nnz2, nnz3;
    int G0, G1, G2, G3;           // partition grids (<=256 each)
    int nb0, nb1, nb2, nb3;       // bucket counts
    int co0, co1, co2, co3;       // cnt-table offsets
};

// ---- cooperative: cnt phase (all graphs) -> grid sync -> scan phase ----
__global__ void __launch_bounds__(256)
k_cntscan(BuildP p, int* cnt, int* bktcur) {
    cg::grid_group gg = cg::this_grid();
    __shared__ int lcnt[MAXB];
    __shared__ int sv[256];
    int t = threadIdx.x;
    int Gsum = p.G0 + p.G1 + p.G2 + p.G3;
    for (int blk = blockIdx.x; blk < Gsum; blk += gridDim.x) {
        int rel, nnz, G, nbuck, co; const int* rows;
        if (blk < p.G0)                   { rel=blk;                 rows=p.r0; nnz=p.nnz0; G=p.G0; nbuck=p.nb0; co=p.co0; }
        else if (blk < p.G0+p.G1)         { rel=blk-p.G0;            rows=p.r1; nnz=p.nnz1; G=p.G1; nbuck=p.nb1; co=p.co1; }
        else if (blk < p.G0+p.G1+p.G2)    { rel=blk-p.G0-p.G1;       rows=p.r2; nnz=p.nnz2; G=p.G2; nbuck=p.nb2; co=p.co2; }
        else                              { rel=blk-p.G0-p.G1-p.G2;  rows=p.r3; nnz=p.nnz3; G=p.G3; nbuck=p.nb3; co=p.co3; }
        __syncthreads();                               // LDS reuse guard
        for (int i = t; i < nbuck; i += 256) lcnt[i] = 0;
        __syncthreads();
        int e0 = rel * PTILE, e1 = min(e0 + PTILE, nnz);
        int e = e0 + t;
        for (; e + 1792 < e1; e += 2048) {             // 8-way ILP
            int r[8];
            #pragma unroll
            for (int k = 0; k < 8; k++) r[k] = rows[e + k * 256];
            #pragma unroll
            for (int k = 0; k < 8; k++) atomicAdd(&lcnt[r[k] >> 7], 1);
        }
        for (; e < e1; e += 256) atomicAdd(&lcnt[rows[e] >> 7], 1);
        __syncthreads();
        for (int b = t; b < nbuck; b += 256) cnt[co + (size_t)b * G + rel] = lcnt[b];
    }
    gg.sync();
    int nbsum = p.nb0 + p.nb1 + p.nb2 + p.nb3;
    for (int bk = blockIdx.x; bk < nbsum; bk += gridDim.x) {
        int seg, rel, G, co;
        if (bk < p.nb0)                    { seg=0; rel=bk;                   G=p.G0; co=p.co0; }
        else if (bk < p.nb0+p.nb1)         { seg=1; rel=bk-p.nb0;             G=p.G1; co=p.co1; }
        else if (bk < p.nb0+p.nb1+p.nb2)   { seg=2; rel=bk-p.nb0-p.nb1;       G=p.G2; co=p.co2; }
        else                               { seg=3; rel=bk-p.nb0-p.nb1-p.nb2; G=p.G3; co=p.co3; }
        int x = (t < G) ? cnt[co + (size_t)rel * G + t] : 0;
        __syncthreads();                               // sv reuse guard
        sv[t] = x;
        __syncthreads();
        for (int off = 1; off < 256; off <<= 1) {      // Hillis-Steele inclusive
            int y = (t >= off) ? sv[t - off] : 0;
            __syncthreads();
            sv[t] += y;
            __syncthreads();
        }
        int bb = bbase(seg, rel);
        if (t < G) cnt[co + (size_t)rel * G + t] = bb + sv[t] - x;   // exclusive base
        if (t == 255) bktcur[seg * MAXB + rel] = bb + sv[255];       // bucket end
    }
}

struct GP {                       // per-graph fused pipeline parameters
    const int* rows; const int* cols;
    const int* cnt;               // exclusive (block,bucket) bases
    int* ep;
    const int* bktcur;
    int* ecolS; int* rowstart; int* rowend; float* scale;
    const float* rawA; const float* rawB_adj;
    ushort* fb; ushort* gb;
    float* accA; float* accB;
    const float* spx; float* spy;
    float inv0, inv1;
    int nnz, G, nbuck, seg, n, mode, do_pad, do_stage, do_layers, do_spmm, spn;
};

// ---- layer phase: fused CSR-SpMM + scale + l2norm + acc (4 rows/wave) ----
__device__ __forceinline__ void layer_phase(const GP& P, const ushort* x,
                                            ushort* fout, float inv,
                                            int write_f, int init) {
    if (write_f && blockIdx.x == 0 && threadIdx.x < 16)   // zero redirect row
        ((ushort4*)(fout + ((size_t)P.n << 6)))[threadIdx.x] = make_ushort4(0, 0, 0, 0);
    const int lane = threadIdx.x & 63;
    const int qtr  = lane >> 4;                   // which of the wave's 4 rows
    const int ql   = lane & 15;
    const int g = ql >> 3, q = ql & 7;            // edge parity, dim chunk (16B)
    const uint4* xb = (const uint4*)x;            // row r, chunk q at r*8+q
    int nq = (P.n + 15) >> 4;
    for (int blk = blockIdx.x; blk < nq; blk += gridDim.x) {
        int rowA = (blk << 4) + ((threadIdx.x >> 6) << 2);
        if (rowA >= P.n) continue;                // no syncthreads below: safe
        int row = rowA + qtr;
        int s = 0, e = 0;
        if (row < P.n) { s = P.rowstart[row]; e = P.rowend[row]; }
        float a0=0.f,a1=0.f,a2=0.f,a3=0.f,a4=0.f,a5=0.f,a6=0.f,a7=0.f;
#define LDQ(m, vv) { int c_ = __shfl(cj, (qtr << 4) + ((m) << 1) + g, 64); \
                     vv = xb[((size_t)(unsigned)c_ << 3) + (unsigned)q]; }
#define ACCQ(vv) { \
    a0 += __uint_as_float(vv.x << 16); a1 += __uint_as_float(vv.x & 0xFFFF0000u); \
    a2 += __uint_as_float(vv.y << 16); a3 += __uint_as_float(vv.y & 0xFFFF0000u); \
    a4 += __uint_as_float(vv.z << 16); a5 += __uint_as_float(vv.z & 0xFFFF0000u); \
    a6 += __uint_as_float(vv.w << 16); a7 += __uint_as_float(vv.w & 0xFFFF0000u); }
        for (int base = s; base < e; base += 16) {
            int jn = e - base;                    // 8 or 16 (x8-padded rows)
            int cj = P.ecolS[base + ql];
            uint4 v0, v1, v2, v3, v4, v5, v6, v7;
            if (jn >= 16) {
                LDQ(0, v0); LDQ(1, v1); LDQ(2, v2); LDQ(3, v3);
                LDQ(4, v4); ACCQ(v0);
                LDQ(5, v5); ACCQ(v1);
                LDQ(6, v6); ACCQ(v2);
                LDQ(7, v7); ACCQ(v3);
                ACCQ(v4); ACCQ(v5); ACCQ(v6); ACCQ(v7);
            } else {
                LDQ(0, v0); LDQ(1, v1); LDQ(2, v2); LDQ(3, v3);
                ACCQ(v0); ACCQ(v1); ACCQ(v2); ACCQ(v3);
            }
        }
#undef LDQ
#undef ACCQ
#define RED(aa) { aa += __shfl_xor(aa, 8, 64); }
        RED(a0) RED(a1) RED(a2) RED(a3) RED(a4) RED(a5) RED(a6) RED(a7)
#undef RED
        float srow = (row < P.n) ? P.scale[row] : 0.f;
        float mlt = srow * inv;
        float w0=a0*mlt, w1=a1*mlt, w2=a2*mlt, w3=a3*mlt;
        float w4=a4*mlt, w5=a5*mlt, w6=a6*mlt, w7=a7*mlt;
        float sq = w0*w0 + w1*w1 + w2*w2 + w3*w3 + w4*w4 + w5*w5 + w6*w6 + w7*w7;
        sq += __shfl_xor(sq, 1, 64); sq += __shfl_xor(sq, 2, 64); sq += __shfl_xor(sq, 4, 64);
        float rn = 1.0f / fmaxf(sqrtf(sq), 1e-12f);
        if (row < P.n && g == 0) {                // 8 lanes per quarter own the row
            size_t o = ((size_t)row << 6) + ((unsigned)q << 3);
            if (write_f) {                        // premult bf16 for next layer
                unsigned p0 = (unsigned)f2bf(w0*srow) | ((unsigned)f2bf(w1*srow) << 16);
                unsigned p1 = (unsigned)f2bf(w2*srow) | ((unsigned)f2bf(w3*srow) << 16);
                unsigned p2 = (unsigned)f2bf(w4*srow) | ((unsigned)f2bf(w5*srow) << 16);
                unsigned p3 = (unsigned)f2bf(w6*srow) | ((unsigned)f2bf(w7*srow) << 16);
                *(uint4*)(fout + o) = make_uint4(p0, p1, p2, p3);
            }
            float r0=w0*rn, r1=w1*rn, r2=w2*rn, r3=w3*rn;
            float r4=w4*rn, r5=w5*rn, r6=w6*rn, r7=w7*rn;
            float* p = (row < U_) ? P.accA + o : P.accB + (o - ((size_t)U_ << 6));
            float4 c0, c1;
            if (init) {
                const float4* rp = (const float4*)((row < U_) ? P.rawA : P.rawB_adj)
                                   + ((size_t)row << 4) + ((unsigned)q << 1);
                c0 = rp[0]; c1 = rp[1];
            } else {
                c0 = ((const float4*)p)[0]; c1 = ((const float4*)p)[1];
            }
            ((float4*)p)[0] = make_float4(c0.x + r0, c0.y + r1, c0.z + r2, c0.w + r3);
            ((float4*)p)[1] = make_float4(c1.x + r4, c1.y + r5, c1.z + r6, c1.w + r7);
        }
    }
}

// ---- spmm phase: plain fp32 CSR-SpMM with row scaling (bundle aggregation) ----
__device__ void spmm_phase(const GP& P) {
    int lane = threadIdx.x & 63;
    int nb4 = (P.spn + 3) >> 2;
    for (int blk = blockIdx.x; blk < nb4; blk += gridDim.x) {
        int row = (blk << 2) + (threadIdx.x >> 6);
        if (row >= P.spn) continue;
        int s = P.rowstart[row], e = P.rowend[row];
        float acc = 0.f;
        for (int base = s; base < e; base += 64) {
            int jn = e - base; if (jn > 64) jn = 64;
            int li = base + (lane < jn ? lane : jn - 1);
            int cj = P.ecolS[li];
            int j = 0;
            for (; j + 8 <= jn; j += 8) {
                int c0 = __shfl(cj, j + 0, 64), c1 = __shfl(cj, j + 1, 64);
                int c2 = __shfl(cj, j + 2, 64), c3 = __shfl(cj, j + 3, 64);
                int c4 = __shfl(cj, j + 4, 64), c5 = __shfl(cj, j + 5, 64);
                int c6 = __shfl(cj, j + 6, 64), c7 = __shfl(cj, j + 7, 64);
                float v0 = P.spx[(size_t)c0 * D + lane], v1 = P.spx[(size_t)c1 * D + lane];
                float v2 = P.spx[(size_t)c2 * D + lane], v3 = P.spx[(size_t)c3 * D + lane];
                float v4 = P.spx[(size_t)c4 * D + lane], v5 = P.spx[(size_t)c5 * D + lane];
                float v6 = P.spx[(size_t)c6 * D + lane], v7 = P.spx[(size_t)c7 * D + lane];
                acc += ((v0 + v1) + (v2 + v3)) + ((v4 + v5) + (v6 + v7));
            }
            for (; j < jn; j++) {
                int c = __shfl(cj, j, 64);
                acc += P.spx[(size_t)c * D + lane];
            }
        }
        P.spy[(size_t)row * D + lane] = acc * P.scale[row];
    }
}

// ---- cooperative per-graph pipeline: scat -> sort -> layer0 -> layer1 [-> spmm] ----
__global__ void __launch_bounds__(256)
k_graph(GP P) {
    cg::grid_group gg = cg::this_grid();
    int t = threadIdx.x;
    // ---- phase 1: scatter edges to exact positions (packed 4B) ----
    {
        __shared__ int lbase[MAXB], lcnt[MAXB], llim[MAXB];
        for (int blk = blockIdx.x; blk < P.G; blk += gridDim.x) {
            __syncthreads();                       // LDS reuse guard
            for (int b = t; b < P.nbuck; b += 256) {
                lbase[b] = P.cnt[(size_t)b * P.G + blk];
                llim[b]  = bbase(P.seg, b + 1);
                lcnt[b]  = 0;
            }
            __syncthreads();
            int e0 = blk * PTILE, e1 = min(e0 + PTILE, P.nnz);
            int e = e0 + t;
            for (; e + 1792 < e1; e += 2048) {     // 8-way ILP
                int r[8], c[8];
                #pragma unroll
                for (int k = 0; k < 8; k++) { r[k] = P.rows[e + k * 256]; c[k] = P.cols[e + k * 256]; }
                #pragma unroll
                for (int k = 0; k < 8; k++) {
                    int b = r[k] >> 7;
                    int pos = lbase[b] + atomicAdd(&lcnt[b], 1);
                    if (pos < llim[b])             // overflow guard (>=9 sigma)
                        P.ep[pos] = ((r[k] & (RPB - 1)) << 17) | c[k];
                }
            }
            for (; e < e1; e += 256) {
                int r = P.rows[e], c = P.cols[e];
                int b = r >> 7;
                int pos = lbase[b] + atomicAdd(&lcnt[b], 1);
                if (pos < llim[b])
                    P.ep[pos] = ((r & (RPB - 1)) << 17) | c;
            }
        }
    }
    gg.sync();
    // ---- phase 2: per-bucket counting sort -> padded CSR + scale + bf16 stage ----
    {
        __shared__ int lc[4 * 129];                // 4 replicas, stride 129
        __shared__ float sscale[RPB];
        __shared__ int wtot;
        for (int b = blockIdx.x; b < P.nbuck; b += gridDim.x) {
            __syncthreads();                       // LDS reuse guard
            int s = bbase(P.seg, b);
            int e = min(P.bktcur[b], bbase(P.seg, b + 1));
            int ne = e - s;
            for (int i = t; i < 4 * 129; i += 256) lc[i] = 0;
            __syncthreads();
            int rep = (t & 3) * 129;
            int i = t;
            for (; i + 768 < ne; i += 1024) {      // 4-way ILP histogram
                int p0 = P.ep[s+i], p1 = P.ep[s+i+256], p2 = P.ep[s+i+512], p3 = P.ep[s+i+768];
                atomicAdd(&lc[rep + (p0 >> 17)], 1); atomicAdd(&lc[rep + (p1 >> 17)], 1);
                atomicAdd(&lc[rep + (p2 >> 17)], 1); atomicAdd(&lc[rep + (p3 >> 17)], 1);
            }
            for (; i < ne; i += 256) { int p = P.ep[s + i]; atomicAdd(&lc[rep + (p >> 17)], 1); }
            __syncthreads();
            int c_t = 0, pc_t = 0, v = 0;
            if (t < RPB) {                         // waves 0,1: counts + wave scan
                c_t = lc[t] + lc[129 + t] + lc[258 + t] + lc[387 + t];
                pc_t = P.do_pad ? ((c_t + 7) & ~7) : c_t;
                v = pc_t;
                for (int off = 1; off < 64; off <<= 1) {
                    int y = __shfl_up(v, off, 64);
                    if ((t & 63) >= off) v += y;
                }
            }
            if (t == 63) wtot = v;
            __syncthreads();
            if (t >= 64 && t < RPB) v += wtot;     // wave 1 adds wave 0 total
            if (t < RPB) {
                int row = b * RPB + t;
                if (row < P.n) {
                    int st = s + (v - pc_t);       // exclusive prefix
                    P.rowstart[row] = st;
                    P.rowend[row]   = st + pc_t;   // PADDED end
                    float sc = (P.mode == 0) ? 1.0f / (sqrtf((float)c_t) + 1e-8f)
                                             : 1.0f / (float)max(c_t, 1);
                    P.scale[row] = sc;
                    sscale[t] = sc;
                    for (int k = c_t; k < pc_t; k++) P.ecolS[st + k] = P.n; // pad->zero row
                    lc[t] = st;                    // replica 0 becomes write cursor
                } else lc[t] = 0;
            }
            __syncthreads();
            i = t;
            for (; i + 768 < ne; i += 1024) {      // 4-way ILP placement (ep: L2 hit)
                int p0 = P.ep[s+i], p1 = P.ep[s+i+256], p2 = P.ep[s+i+512], p3 = P.ep[s+i+768];
                int q0 = atomicAdd(&lc[p0 >> 17], 1); P.ecolS[q0] = p0 & 0x1FFFF;
                int q1 = atomicAdd(&lc[p1 >> 17], 1); P.ecolS[q1] = p1 & 0x1FFFF;
                int q2 = atomicAdd(&lc[p2 >> 17], 1); P.ecolS[q2] = p2 & 0x1FFFF;
                int q3 = atomicAdd(&lc[p3 >> 17], 1); P.ecolS[q3] = p3 & 0x1FFFF;
            }
            for (; i < ne; i += 256) {
                int p = P.ep[s + i];
                int q = atomicAdd(&lc[p >> 17], 1);
                P.ecolS[q] = p & 0x1FFFF;
            }
            if (P.do_stage) {                      // fused premultiplied bf16 stage
                int r0 = b * RPB;
                for (int idx = t; idx < RPB * 16; idx += 256) {
                    int rl = idx >> 4, q = idx & 15;
                    int row = r0 + rl;
                    if (row > P.n) continue;
                    ushort4 o;
                    if (row == P.n) {
                        o = make_ushort4(0, 0, 0, 0);
                    } else {
                        float sc = sscale[rl];
                        float4 vv = (row < U_) ? ((const float4*)P.rawA)[(size_t)row * 16 + q]
                                               : ((const float4*)P.rawB_adj)[(size_t)row * 16 + q];
                        o.x = f2bf(vv.x * sc); o.y = f2bf(vv.y * sc);
                        o.z = f2bf(vv.z * sc); o.w = f2bf(vv.w * sc);
                    }
                    ((ushort4*)P.fb)[(size_t)row * 16 + q] = o;
                }
            }
        }
    }
    gg.sync();
    if (P.do_layers) {
        // layer 0: y0 = s.*spmm(fb)/2 ; acc = raw + l2norm(y0); gb = bf16(s.*y0)
        layer_phase(P, P.fb, P.gb, P.inv0, 1, 1);
        gg.sync();
        // layer 1: y1 = s.*spmm(gb)/3 ; acc += l2norm(y1)
        layer_phase(P, P.gb, (ushort*)nullptr, P.inv1, 0, 0);
    }
    if (P.do_spmm) spmm_phase(P);                  // agg: IL_b = agg @ acc_itm
}

extern "C" void kernel_launch(void* const* d_in, const int* in_sizes, int n_in,
                              void* d_out, int out_size, void* d_ws, size_t ws_size,
                              hipStream_t stream) {
    const float* users   = (const float*)d_in[0];
    const float* bundles = (const float*)d_in[1];
    const float* items   = (const float*)d_in[2];
    const int*   ui_idx  = (const int*)d_in[3];
    const int*   ub_idx  = (const int*)d_in[5];
    const int*   ubx_idx = (const int*)d_in[7];
    const int*   agg_idx = (const int*)d_in[9];
    const int ui_nnz  = in_sizes[4];
    const int ub_nnz  = in_sizes[6];
    const int ubx_nnz = in_sizes[8];
    const int agg_nnz = in_sizes[10];

    float* out = (float*)d_out;
    const size_t rowf = (size_t)D;

    // ---- workspace carve-up (~49.7 MB, byte-identical to round 8) ----
    const int NROWPAD = 90004;
    const int EPMAX   = 547 * 6144;                   // 3,360,768
    ushort* fb16    = (ushort*)d_ws;                  // 11.52 MB staged bf16
    float*  acc_itm = (float*)(fb16 + (size_t)(90001) * D + 32);
    float*  scale   = acc_itm + (size_t)I_ * D;
    int*    ep      = (int*)(scale + NROWPAD);        // 13.44 MB bucket regions
    ushort* gb16    = (ushort*)ep;                    // ALIASES ep (dead after sort)
    int*    ecolS   = ep + EPMAX;                     // 13.44 MB row-sorted cols
    int*    rowstart= ecolS + EPMAX;
    int*    rowend  = rowstart + NROWPAD;
    int*    bktcur  = rowend + NROWPAD;
    int*    cnt     = ep + 2950000;                   // dead tail of ep region

    // ---- output layout ----
    float* out_IL_u = out;
    float* out_BL_u = out + (size_t)U_ * rowf;
    float* out_XL_u = out + (size_t)2 * U_ * rowf;
    float* out_IL_b = out + (size_t)3 * U_ * rowf;
    float* out_BL_b = out + (size_t)3 * U_ * rowf + (size_t)B_ * rowf;
    float* out_XL_b = out + (size_t)3 * U_ * rowf + (size_t)2 * B_ * rowf;

    // ---- fused count + scan parameters (seg: 0=ui 1=agg 2=ub 3=ubx) ----
    BuildP P;
    P.r0 = ui_idx;  P.nnz0 = ui_nnz;  P.G0 = (ui_nnz  + PTILE - 1) / PTILE;  P.nb0 = 704;
    P.r1 = agg_idx; P.nnz1 = agg_nnz; P.G1 = (agg_nnz + PTILE - 1) / PTILE;  P.nb1 = 157;
    P.r2 = ub_idx;  P.nnz2 = ub_nnz;  P.G2 = (ub_nnz  + PTILE - 1) / PTILE;  P.nb2 = 547;
    P.r3 = ubx_idx; P.nnz3 = ubx_nnz; P.G3 = (ubx_nnz + PTILE - 1) / PTILE;  P.nb3 = 547;
    P.co0 = 0;
    P.co1 = P.co0 + P.nb0 * P.G0;
    P.co2 = P.co1 + P.nb1 * P.G1;
    P.co3 = P.co2 + P.nb2 * P.G2;

    // cooperative grids sized to guaranteed co-residency (256 CUs)
    int mbA = 1, mbG = 1;
    hipOccupancyMaxActiveBlocksPerMultiprocessor(&mbA, k_cntscan, 256, 0);
    hipOccupancyMaxActiveBlocksPerMultiprocessor(&mbG, k_graph, 256, 0);
    if (mbA < 1) mbA = 1;
    if (mbG < 1) mbG = 1;
    int gridA = min(2048, mbA * 256);
    int gridG = min(2048, mbG * 256);

    void* argsA[] = { (void*)&P, (void*)&cnt, (void*)&bktcur };
    hipLaunchCooperativeKernel(k_cntscan, dim3(gridA), dim3(256), argsA, 0, stream);

    auto mkgp = [&](const int* idxp, int nnz, int n, int mode, int do_pad,
                    int do_stage, const float* A, const float* Badj,
                    int seg, int G, int co, int do_layers,
                    float* accA, float* accB,
                    int do_spmm, const float* spx, float* spy, int spn) {
        GP g{};
        g.rows = idxp; g.cols = idxp + nnz; g.nnz = nnz; g.G = G;
        g.nbuck = (n + RPB - 1) / RPB; g.seg = seg; g.n = n; g.mode = mode;
        g.do_pad = do_pad; g.do_stage = do_stage; g.do_layers = do_layers;
        g.do_spmm = do_spmm; g.spn = spn;
        g.cnt = cnt + co; g.ep = ep; g.bktcur = bktcur + seg * MAXB;
        g.ecolS = ecolS; g.rowstart = rowstart; g.rowend = rowend; g.scale = scale;
        g.rawA = A; g.rawB_adj = Badj; g.fb = fb16; g.gb = gb16;
        g.accA = accA; g.accB = accB; g.spx = spx; g.spy = spy;
        g.inv0 = 0.5f; g.inv1 = 1.0f / 3.0f;
        return g;
    };
    auto launch_g = [&](GP& g) {
        void* args[] = { (void*)&g };
        hipLaunchCooperativeKernel(k_graph, dim3(gridG), dim3(256), args, 0, stream);
    };

    // item-level propagation over user-item graph
    GP gui = mkgp(ui_idx, ui_nnz, U_ + I_, 0, 1, 1, users, items - (size_t)U_ * rowf,
                  0, P.G0, P.co0, 1, out_IL_u, acc_itm, 0, nullptr, nullptr, 0);
    launch_g(gui);

    // bundle aggregation: build agg CSR then IL_b = agg @ acc_itm (after ui layers)
    GP gagg = mkgp(agg_idx, agg_nnz, B_, 1, 0, 0, users, users,
                   1, P.G1, P.co1, 0, nullptr, nullptr, 1, acc_itm, out_IL_b, B_);
    launch_g(gagg);

    // bundle-level propagation over user-bundle graph
    GP gub = mkgp(ub_idx, ub_nnz, U_ + B_, 0, 1, 1, users, bundles - (size_t)U_ * rowf,
                  2, P.G2, P.co2, 1, out_BL_u, out_BL_b, 0, nullptr, nullptr, 0);
    launch_g(gub);

    // ingredient-augmented user-bundle propagation
    GP gubx = mkgp(ubx_idx, ubx_nnz, U_ + B_, 0, 1, 1, users, bundles - (size_t)U_ * rowf,
                   3, P.G3, P.co3, 1, out_XL_u, out_XL_b, 0, nullptr, nullptr, 0);
    launch_g(gubx);
}

// Round 10
// 431.284 us; speedup vs baseline: 4.0507x; 4.0507x over previous
//
#include <hip/hip_runtime.h>

#define D 64
constexpr int U_ = 50000, B_ = 20000, I_ = 40000;
constexpr int RPB  = 128;
constexpr int MAXB = 708;
constexpr int PTILE = 8192;

// Side-dependent bucket capacities (exact counts + x8 row padding + >=9 sigma).
constexpr int NBU = 390;
constexpr int CAPU_UI = 3584, CAPB_UI = 4352;   // deg 20 / 25 per row
constexpr int CAPA    = 2560;                   // agg: unpadded rows, deg 15
constexpr int CAPU_UB = 2432, CAPB_UB = 4864;   // deg 12 / 30
constexpr int CAPU_UX = 2944, CAPB_UX = 6272;   // deg 16 / 40
// per-graph ep/ecol extents
constexpr int EXT_UI = NBU * CAPU_UI + 314 * CAPB_UI;  // 2,764,288
constexpr int EXT_AG = 157 * CAPA;                     //   401,920
constexpr int EXT_UB = NBU * CAPU_UB + 157 * CAPB_UB;  // 1,712,128
constexpr int EXT_UX = NBU * CAPU_UX + 157 * CAPB_UX;  // 2,132,864
constexpr long long EXT_SUM = (long long)EXT_UI + EXT_AG + EXT_UB + EXT_UX; // 7,011,200

__device__ __forceinline__ int g_nbU(int seg) { return seg == 1 ? 0 : NBU; }
__device__ __forceinline__ int g_capU(int seg) {
    switch (seg) { case 0: return CAPU_UI; case 1: return CAPA;
                   case 2: return CAPU_UB; default: return CAPU_UX; }
}
__device__ __forceinline__ int g_capB(int seg) {
    switch (seg) { case 0: return CAPB_UI; case 1: return CAPA;
                   case 2: return CAPB_UB; default: return CAPB_UX; }
}
__device__ __forceinline__ int bbase(int seg, int b) {   // graph-local region start
    int nbU = g_nbU(seg);
    return (b <= nbU) ? b * g_capU(seg)
                      : nbU * g_capU(seg) + (b - nbU) * g_capB(seg);
}

__device__ __forceinline__ unsigned short f2bf(float f) {   // RTN-even
    unsigned int u = __float_as_uint(f);
    return (unsigned short)((u + 0x7FFFu + ((u >> 16) & 1u)) >> 16);
}

struct GD {                       // per-graph build descriptor (graph-local bases)
    const int* rows; const int* cols;
    int* ep; int* cnt; int* bktcur;
    int* ecol; int* rowstart; int* rowend; float* scale;
    const float* rawA; const float* rawB_adj;
    ushort* fb;
    int nnz, G, nbuck, seg, n, mode, do_pad, do_stage;
};
struct GB4 { GD g[4]; int ng; int Gpre[5]; int nbpre[5]; };

// ---- batched cnt: per-(block,bucket) histogram -> cnt[b*G + rel] ----
__global__ void __launch_bounds__(256) k_cntB(GB4 P) {
    __shared__ int lcnt[MAXB];
    int blk = blockIdx.x, t = threadIdx.x;
    int gi = 0;
    while (gi + 1 < P.ng && blk >= P.Gpre[gi + 1]) gi++;
    const GD& d = P.g[gi];
    int rel = blk - P.Gpre[gi];
    const int* __restrict__ rows = d.rows;
    for (int i = t; i < d.nbuck; i += 256) lcnt[i] = 0;
    __syncthreads();
    int e0 = rel * PTILE, e1 = min(e0 + PTILE, d.nnz);
    int e = e0 + t;
    for (; e + 1792 < e1; e += 2048) {             // 8-way ILP
        int r[8];
        #pragma unroll
        for (int k = 0; k < 8; k++) r[k] = rows[e + k * 256];
        #pragma unroll
        for (int k = 0; k < 8; k++) atomicAdd(&lcnt[r[k] >> 7], 1);
    }
    for (; e < e1; e += 256) atomicAdd(&lcnt[rows[e] >> 7], 1);
    __syncthreads();
    for (int b = t; b < d.nbuck; b += 256) d.cnt[(size_t)b * d.G + rel] = lcnt[b];
}

// ---- batched scan: per-bucket exclusive prefix over blocks (G <= 256) ----
__global__ void __launch_bounds__(256) k_scanB(GB4 P) {
    __shared__ int sv[256];
    int bk = blockIdx.x, t = threadIdx.x;
    int gi = 0;
    while (gi + 1 < P.ng && bk >= P.nbpre[gi + 1]) gi++;
    const GD& d = P.g[gi];
    int rel = bk - P.nbpre[gi];
    int x = (t < d.G) ? d.cnt[(size_t)rel * d.G + t] : 0;
    sv[t] = x;
    __syncthreads();
    for (int off = 1; off < 256; off <<= 1) {      // Hillis-Steele inclusive
        int y = (t >= off) ? sv[t - off] : 0;
        __syncthreads();
        sv[t] += y;
        __syncthreads();
    }
    int bb = bbase(d.seg, rel);
    if (t < d.G) d.cnt[(size_t)rel * d.G + t] = bb + sv[t] - x;   // exclusive base
    if (t == 255) d.bktcur[rel] = bb + sv[255];                   // bucket end
}

// ---- batched scatter: edges to exact graph-local positions (packed 4B) ----
__global__ void __launch_bounds__(256) k_scatB(GB4 P) {
    __shared__ int lbase[MAXB], lcnt[MAXB], llim[MAXB];
    int blk = blockIdx.x, t = threadIdx.x;
    int gi = 0;
    while (gi + 1 < P.ng && blk >= P.Gpre[gi + 1]) gi++;
    const GD& d = P.g[gi];
    int rel = blk - P.Gpre[gi];
    const int* __restrict__ rows = d.rows;
    const int* __restrict__ cols = d.cols;
    int* __restrict__ ep = d.ep;
    for (int b = t; b < d.nbuck; b += 256) {
        lbase[b] = d.cnt[(size_t)b * d.G + rel];
        llim[b]  = bbase(d.seg, b + 1);
        lcnt[b]  = 0;
    }
    __syncthreads();
    int e0 = rel * PTILE, e1 = min(e0 + PTILE, d.nnz);
    int e = e0 + t;
    for (; e + 1792 < e1; e += 2048) {             // 8-way ILP
        int r[8], c[8];
        #pragma unroll
        for (int k = 0; k < 8; k++) { r[k] = rows[e + k * 256]; c[k] = cols[e + k * 256]; }
        #pragma unroll
        for (int k = 0; k < 8; k++) {
            int b = r[k] >> 7;
            int pos = lbase[b] + atomicAdd(&lcnt[b], 1);
            if (pos < llim[b])                     // overflow guard (>=9 sigma)
                ep[pos] = ((r[k] & (RPB - 1)) << 17) | c[k];
        }
    }
    for (; e < e1; e += 256) {
        int r = rows[e], c = cols[e];
        int b = r >> 7;
        int pos = lbase[b] + atomicAdd(&lcnt[b], 1);
        if (pos < llim[b])
            ep[pos] = ((r & (RPB - 1)) << 17) | c;
    }
}

// ---- batched counting sort -> padded CSR + scale + fused bf16 stage ----
__global__ void __launch_bounds__(256) k_sortB(GB4 P) {
    __shared__ int lc[4 * 129];                    // 4 replicas, stride 129
    __shared__ float sscale[RPB];
    __shared__ int wtot;
    int bk = blockIdx.x, t = threadIdx.x;
    int gi = 0;
    while (gi + 1 < P.ng && bk >= P.nbpre[gi + 1]) gi++;
    const GD& d = P.g[gi];
    int b = bk - P.nbpre[gi];
    const int* __restrict__ ep = d.ep;
    int* __restrict__ ecol = d.ecol;
    int s = bbase(d.seg, b);
    int e = min(d.bktcur[b], bbase(d.seg, b + 1));
    int ne = e - s;
    for (int i = t; i < 4 * 129; i += 256) lc[i] = 0;
    __syncthreads();
    int rep = (t & 3) * 129;
    int i = t;
    for (; i + 768 < ne; i += 1024) {              // 4-way ILP histogram
        int p0 = ep[s+i], p1 = ep[s+i+256], p2 = ep[s+i+512], p3 = ep[s+i+768];
        atomicAdd(&lc[rep + (p0 >> 17)], 1); atomicAdd(&lc[rep + (p1 >> 17)], 1);
        atomicAdd(&lc[rep + (p2 >> 17)], 1); atomicAdd(&lc[rep + (p3 >> 17)], 1);
    }
    for (; i < ne; i += 256) { int p = ep[s + i]; atomicAdd(&lc[rep + (p >> 17)], 1); }
    __syncthreads();
    int c_t = 0, pc_t = 0, v = 0;
    if (t < RPB) {                                 // waves 0,1: counts + wave scan
        c_t = lc[t] + lc[129 + t] + lc[258 + t] + lc[387 + t];
        pc_t = d.do_pad ? ((c_t + 7) & ~7) : c_t;
        v = pc_t;
        for (int off = 1; off < 64; off <<= 1) {
            int y = __shfl_up(v, off, 64);
            if ((t & 63) >= off) v += y;
        }
    }
    if (t == 63) wtot = v;
    __syncthreads();
    if (t >= 64 && t < RPB) v += wtot;             // wave 1 adds wave 0 total
    if (t < RPB) {
        int row = b * RPB + t;
        if (row < d.n) {
            int st = s + (v - pc_t);               // exclusive prefix
            d.rowstart[row] = st;
            d.rowend[row]   = st + pc_t;           // PADDED end
            float sc = (d.mode == 0) ? 1.0f / (sqrtf((float)c_t) + 1e-8f)
                                     : 1.0f / (float)max(c_t, 1);
            d.scale[row] = sc;
            sscale[t] = sc;
            for (int k = c_t; k < pc_t; k++) ecol[st + k] = d.n;  // pad -> zero row
            lc[t] = st;                            // replica 0 becomes write cursor
        } else lc[t] = 0;
    }
    __syncthreads();
    i = t;
    for (; i + 768 < ne; i += 1024) {              // 4-way ILP placement
        int p0 = ep[s+i], p1 = ep[s+i+256], p2 = ep[s+i+512], p3 = ep[s+i+768];
        int q0 = atomicAdd(&lc[p0 >> 17], 1); ecol[q0] = p0 & 0x1FFFF;
        int q1 = atomicAdd(&lc[p1 >> 17], 1); ecol[q1] = p1 & 0x1FFFF;
        int q2 = atomicAdd(&lc[p2 >> 17], 1); ecol[q2] = p2 & 0x1FFFF;
        int q3 = atomicAdd(&lc[p3 >> 17], 1); ecol[q3] = p3 & 0x1FFFF;
    }
    for (; i < ne; i += 256) {
        int p = ep[s + i];
        int q = atomicAdd(&lc[p >> 17], 1);
        ecol[q] = p & 0x1FFFF;
    }
    if (d.do_stage) {                              // fused premultiplied bf16 stage
        int r0 = b * RPB;
        for (int idx = t; idx < RPB * 16; idx += 256) {
            int rl = idx >> 4, q = idx & 15;
            int row = r0 + rl;
            if (row > d.n) continue;
            ushort4 o;
            if (row == d.n) {
                o = make_ushort4(0, 0, 0, 0);      // zero redirect row
            } else {
                float sc = sscale[rl];
                float4 vv = (row < U_) ? ((const float4*)d.rawA)[(size_t)row * 16 + q]
                                       : ((const float4*)d.rawB_adj)[(size_t)row * 16 + q];
                o.x = f2bf(vv.x * sc); o.y = f2bf(vv.y * sc);
                o.z = f2bf(vv.z * sc); o.w = f2bf(vv.w * sc);
            }
            ((ushort4*)d.fb)[(size_t)row * 16 + q] = o;
        }
    }
}

struct LD {                       // per-graph layer descriptor
    const int* rowstart; const int* rowend; const float* scale;
    const int* ecol; const ushort* x; ushort* fout;
    const float* rawA; const float* rawB_adj;
    float* accA; float* accB;
    float inv; int n, write_f, init;
};
struct LB3 { LD l[3]; int nl; int qpre[4]; };

// ---- batched fused CSR-SpMM + scale + l2norm + acc (4 rows/wave) ----
__global__ void __launch_bounds__(256) k_layerB(LB3 P) {
    int blk = blockIdx.x;
    int gi = 0;
    while (gi + 1 < P.nl && blk >= P.qpre[gi + 1]) gi++;
    const LD& d = P.l[gi];
    int rel = blk - P.qpre[gi];
    if (d.write_f && rel == 0 && threadIdx.x < 16)   // zero redirect row of fout
        ((ushort4*)(d.fout + ((size_t)d.n << 6)))[threadIdx.x] = make_ushort4(0, 0, 0, 0);
    const int* __restrict__ rowstart = d.rowstart;
    const int* __restrict__ rowend   = d.rowend;
    const int* __restrict__ ecol     = d.ecol;
    const float* __restrict__ scale  = d.scale;
    const uint4* __restrict__ xb = (const uint4*)d.x;   // row r, chunk q at r*8+q
    const int lane = threadIdx.x & 63;
    const int qtr  = lane >> 4;
    const int ql   = lane & 15;
    const int g = ql >> 3, q = ql & 7;
    int rowA = (rel << 4) + ((threadIdx.x >> 6) << 2);
    if (rowA >= d.n) return;
    int row = rowA + qtr;
    int s = 0, e = 0;
    if (row < d.n) { s = rowstart[row]; e = rowend[row]; }
    float a0=0.f,a1=0.f,a2=0.f,a3=0.f,a4=0.f,a5=0.f,a6=0.f,a7=0.f;
#define LDQ(m, vv) { int c_ = __shfl(cj, (qtr << 4) + ((m) << 1) + g, 64); \
                     vv = xb[((size_t)(unsigned)c_ << 3) + (unsigned)q]; }
#define ACCQ(vv) { \
    a0 += __uint_as_float(vv.x << 16); a1 += __uint_as_float(vv.x & 0xFFFF0000u); \
    a2 += __uint_as_float(vv.y << 16); a3 += __uint_as_float(vv.y & 0xFFFF0000u); \
    a4 += __uint_as_float(vv.z << 16); a5 += __uint_as_float(vv.z & 0xFFFF0000u); \
    a6 += __uint_as_float(vv.w << 16); a7 += __uint_as_float(vv.w & 0xFFFF0000u); }
    for (int base = s; base < e; base += 16) {
        int jn = e - base;                        // 8 or 16 (x8-padded rows)
        int cj = ecol[base + ql];
        uint4 v0, v1, v2, v3, v4, v5, v6, v7;
        if (jn >= 16) {
            LDQ(0, v0); LDQ(1, v1); LDQ(2, v2); LDQ(3, v3);
            LDQ(4, v4); ACCQ(v0);
            LDQ(5, v5); ACCQ(v1);
            LDQ(6, v6); ACCQ(v2);
            LDQ(7, v7); ACCQ(v3);
            ACCQ(v4); ACCQ(v5); ACCQ(v6); ACCQ(v7);
        } else {
            LDQ(0, v0); LDQ(1, v1); LDQ(2, v2); LDQ(3, v3);
            ACCQ(v0); ACCQ(v1); ACCQ(v2); ACCQ(v3);
        }
    }
#undef LDQ
#undef ACCQ
#define RED(aa) { aa += __shfl_xor(aa, 8, 64); }
    RED(a0) RED(a1) RED(a2) RED(a3) RED(a4) RED(a5) RED(a6) RED(a7)
#undef RED
    float srow = (row < d.n) ? scale[row] : 0.f;
    float mlt = srow * d.inv;
    float w0=a0*mlt, w1=a1*mlt, w2=a2*mlt, w3=a3*mlt;
    float w4=a4*mlt, w5=a5*mlt, w6=a6*mlt, w7=a7*mlt;
    float sq = w0*w0 + w1*w1 + w2*w2 + w3*w3 + w4*w4 + w5*w5 + w6*w6 + w7*w7;
    sq += __shfl_xor(sq, 1, 64); sq += __shfl_xor(sq, 2, 64); sq += __shfl_xor(sq, 4, 64);
    float rn = 1.0f / fmaxf(sqrtf(sq), 1e-12f);
    if (row < d.n && g == 0) {                     // 8 lanes per quarter own the row
        size_t o = ((size_t)row << 6) + ((unsigned)q << 3);
        if (d.write_f) {                           // premult bf16 for next layer
            unsigned p0 = (unsigned)f2bf(w0*srow) | ((unsigned)f2bf(w1*srow) << 16);
            unsigned p1 = (unsigned)f2bf(w2*srow) | ((unsigned)f2bf(w3*srow) << 16);
            unsigned p2 = (unsigned)f2bf(w4*srow) | ((unsigned)f2bf(w5*srow) << 16);
            unsigned p3 = (unsigned)f2bf(w6*srow) | ((unsigned)f2bf(w7*srow) << 16);
            *(uint4*)(d.fout + o) = make_uint4(p0, p1, p2, p3);
        }
        float r0=w0*rn, r1=w1*rn, r2=w2*rn, r3=w3*rn;
        float r4=w4*rn, r5=w5*rn, r6=w6*rn, r7=w7*rn;
        float* p = (row < U_) ? d.accA + o : d.accB + (o - ((size_t)U_ << 6));
        float4 c0, c1;
        if (d.init) {
            const float4* rp = (const float4*)((row < U_) ? d.rawA : d.rawB_adj)
                               + ((size_t)row << 4) + ((unsigned)q << 1);
            c0 = rp[0]; c1 = rp[1];
        } else {
            c0 = ((const float4*)p)[0]; c1 = ((const float4*)p)[1];
        }
        ((float4*)p)[0] = make_float4(c0.x + r0, c0.y + r1, c0.z + r2, c0.w + r3);
        ((float4*)p)[1] = make_float4(c1.x + r4, c1.y + r5, c1.z + r6, c1.w + r7);
    }
}

// Plain fp32 CSR-SpMM with row scaling (bundle aggregation, unpadded CSR)
__global__ void k_spmm_csr(const int* __restrict__ rowstart, const int* __restrict__ rowend,
                           const int* __restrict__ ecol,
                           const float* __restrict__ rs, int n,
                           const float* __restrict__ x, float* __restrict__ y) {
    int row = (blockIdx.x << 2) + (threadIdx.x >> 6);
    if (row >= n) return;
    int lane = threadIdx.x & 63;
    int s = rowstart[row], e = rowend[row];
    float acc = 0.f;
    for (int base = s; base < e; base += 64) {
        int jn = e - base; if (jn > 64) jn = 64;
        int li = base + (lane < jn ? lane : jn - 1);
        int cj = ecol[li];
        int j = 0;
        for (; j + 8 <= jn; j += 8) {
            int c0 = __shfl(cj, j + 0, 64), c1 = __shfl(cj, j + 1, 64);
            int c2 = __shfl(cj, j + 2, 64), c3 = __shfl(cj, j + 3, 64);
            int c4 = __shfl(cj, j + 4, 64), c5 = __shfl(cj, j + 5, 64);
            int c6 = __shfl(cj, j + 6, 64), c7 = __shfl(cj, j + 7, 64);
            float v0 = x[(size_t)c0 * D + lane], v1 = x[(size_t)c1 * D + lane];
            float v2 = x[(size_t)c2 * D + lane], v3 = x[(size_t)c3 * D + lane];
            float v4 = x[(size_t)c4 * D + lane], v5 = x[(size_t)c5 * D + lane];
            float v6 = x[(size_t)c6 * D + lane], v7 = x[(size_t)c7 * D + lane];
            acc += ((v0 + v1) + (v2 + v3)) + ((v4 + v5) + (v6 + v7));
        }
        for (; j < jn; j++) {
            int c = __shfl(cj, j, 64);
            acc += x[(size_t)c * D + lane];
        }
    }
    y[(size_t)row * D + lane] = acc * rs[row];
}

extern "C" void kernel_launch(void* const* d_in, const int* in_sizes, int n_in,
                              void* d_out, int out_size, void* d_ws, size_t ws_size,
                              hipStream_t stream) {
    const float* users   = (const float*)d_in[0];
    const float* bundles = (const float*)d_in[1];
    const float* items   = (const float*)d_in[2];
    const int*   ui_idx  = (const int*)d_in[3];
    const int*   ub_idx  = (const int*)d_in[5];
    const int*   ubx_idx = (const int*)d_in[7];
    const int*   agg_idx = (const int*)d_in[9];
    const int ui_nnz  = in_sizes[4];
    const int ub_nnz  = in_sizes[6];
    const int ubx_nnz = in_sizes[8];
    const int agg_nnz = in_sizes[10];

    float* out = (float*)d_out;
    const size_t rowf = (size_t)D;
    float* out_IL_u = out;
    float* out_BL_u = out + (size_t)U_ * rowf;
    float* out_XL_u = out + (size_t)2 * U_ * rowf;
    float* out_IL_b = out + (size_t)3 * U_ * rowf;
    float* out_BL_b = out + (size_t)3 * U_ * rowf + (size_t)B_ * rowf;
    float* out_XL_b = out + (size_t)3 * U_ * rowf + (size_t)2 * B_ * rowf;

    const int G0 = (ui_nnz  + PTILE - 1) / PTILE;
    const int G1 = (agg_nnz + PTILE - 1) / PTILE;
    const int G2 = (ub_nnz  + PTILE - 1) / PTILE;
    const int G3 = (ubx_nnz + PTILE - 1) / PTILE;
    const int NB0 = 704, NB1 = 157, NB2 = 547, NB3 = 547;
    const size_t co0 = 0, co1 = (size_t)NB0 * G0, co2 = co1 + (size_t)NB1 * G1,
                 co3 = co2 + (size_t)NB2 * G2, cntInts = co3 + (size_t)NB3 * G3;
    const int nU = U_ + I_, nB2g = U_ + B_;        // 90000, 70000

    const int* rowsArr[4] = { ui_idx, agg_idx, ub_idx, ubx_idx };
    const int nnzArr[4]   = { ui_nnz, agg_nnz, ub_nnz, ubx_nnz };
    const int GArr[4]     = { G0, G1, G2, G3 };
    const int nbArr[4]    = { NB0, NB1, NB2, NB3 };
    const int nArr[4]     = { nU, B_, nB2g, nB2g };
    const int modeArr[4]  = { 0, 1, 0, 0 };
    const int padArr[4]   = { 1, 0, 1, 1 };
    const int stgArr[4]   = { 1, 0, 1, 1 };
    const size_t coArr[4] = { co0, co1, co2, co3 };
    const float* rawBArr[4] = { items - (size_t)U_ * rowf, users,
                                bundles - (size_t)U_ * rowf, bundles - (size_t)U_ * rowf };

    // ---- Layout A requirement (bytes) ----
    const size_t fbBytes  = 230003ull * 128;       // ui 90001 + ub 70001 + ubx 70001 rows
    const size_t accBytes = 40001ull * 256;
    const size_t ecBytes  = (size_t)EXT_SUM * 4;
    const size_t rsBytes  = 250016ull * 4;         // 90004+20004+70004+70004
    const size_t bkBytes  = 4ull * MAXB * 4;
    const size_t epcnt    = (size_t)EXT_SUM * 4 + cntInts * 4;
    const size_t tailB    = epcnt > fbBytes ? epcnt : fbBytes;   // gb aliases ep+cnt
    const size_t reqA     = fbBytes + accBytes + ecBytes + 3 * rsBytes + bkBytes + tailB + 4096;

    GB4 P{};
    P.ng = 4;
    P.Gpre[0] = 0; P.nbpre[0] = 0;
    for (int i = 0; i < 4; i++) { P.Gpre[i+1] = P.Gpre[i] + GArr[i]; P.nbpre[i+1] = P.nbpre[i] + nbArr[i]; }

    if (ws_size >= reqA) {
        // ================= Layout A: disjoint regions, 7 launches =================
        char* w = (char*)d_ws;
        ushort* fbA   = (ushort*)w;                 w += fbBytes;
        float* accI   = (float*)w;                  w += accBytes;
        int*   ecolA  = (int*)w;                    w += ecBytes;
        int*   rsA    = (int*)w;                    w += rsBytes;
        int*   reA    = (int*)w;                    w += rsBytes;
        float* scA    = (float*)w;                  w += rsBytes;
        int*   bkA    = (int*)w;                    w += bkBytes;
        int*   epA    = (int*)w;                    /* ep then cnt */
        int*   cntA   = epA + EXT_SUM;
        ushort* gbA   = (ushort*)epA;               // aliases ep+cnt (dead after sort4)

        const size_t epoff[4] = { 0, (size_t)EXT_UI, (size_t)EXT_UI + EXT_AG,
                                  (size_t)EXT_UI + EXT_AG + EXT_UB };
        const size_t roff[4]  = { 0, 90004, 110008, 180012 };
        const size_t fboff[4] = { 0, 0, 90001ull * 64, 160002ull * 64 };  // agg unused

        for (int i = 0; i < 4; i++) {
            GD& d = P.g[i];
            d.rows = rowsArr[i]; d.cols = rowsArr[i] + nnzArr[i];
            d.ep = epA + epoff[i]; d.cnt = cntA + coArr[i]; d.bktcur = bkA + i * MAXB;
            d.ecol = ecolA + epoff[i];
            d.rowstart = rsA + roff[i]; d.rowend = reA + roff[i]; d.scale = scA + roff[i];
            d.rawA = users; d.rawB_adj = rawBArr[i];
            d.fb = (i == 1) ? nullptr : fbA + fboff[i];
            d.nnz = nnzArr[i]; d.G = GArr[i]; d.nbuck = nbArr[i]; d.seg = i;
            d.n = nArr[i]; d.mode = modeArr[i]; d.do_pad = padArr[i]; d.do_stage = stgArr[i];
        }
        hipLaunchKernelGGL(k_cntB,  dim3(P.Gpre[4]),  dim3(256), 0, stream, P);
        hipLaunchKernelGGL(k_scanB, dim3(P.nbpre[4]), dim3(256), 0, stream, P);
        hipLaunchKernelGGL(k_scatB, dim3(P.Gpre[4]),  dim3(256), 0, stream, P);
        hipLaunchKernelGGL(k_sortB, dim3(P.nbpre[4]), dim3(256), 0, stream, P);

        float* accAArr[3] = { out_IL_u, out_BL_u, out_XL_u };
        float* accBArr[3] = { accI, out_BL_b, out_XL_b };
        int gsel[3] = { 0, 2, 3 };
        LB3 L{};
        L.nl = 3; L.qpre[0] = 0;
        for (int j = 0; j < 3; j++) {
            int i = gsel[j];
            LD& l = L.l[j];
            l.rowstart = P.g[i].rowstart; l.rowend = P.g[i].rowend; l.scale = P.g[i].scale;
            l.ecol = P.g[i].ecol; l.rawA = users; l.rawB_adj = rawBArr[i];
            l.accA = accAArr[j]; l.accB = accBArr[j];
            l.n = nArr[i];
            L.qpre[j + 1] = L.qpre[j] + ((nArr[i] + 15) >> 4);
        }
        // layer 0
        for (int j = 0; j < 3; j++) {
            int i = gsel[j];
            L.l[j].x = fbA + fboff[i]; L.l[j].fout = gbA + fboff[i];
            L.l[j].inv = 0.5f; L.l[j].write_f = 1; L.l[j].init = 1;
        }
        hipLaunchKernelGGL(k_layerB, dim3(L.qpre[3]), dim3(256), 0, stream, L);
        // layer 1
        for (int j = 0; j < 3; j++) {
            int i = gsel[j];
            L.l[j].x = gbA + fboff[i]; L.l[j].fout = (ushort*)nullptr;
            L.l[j].inv = 1.0f / 3.0f; L.l[j].write_f = 0; L.l[j].init = 0;
        }
        hipLaunchKernelGGL(k_layerB, dim3(L.qpre[3]), dim3(256), 0, stream, L);
        // bundle aggregation: IL_b = agg @ acc_itm
        hipLaunchKernelGGL(k_spmm_csr, dim3((B_ + 3) / 4), dim3(256), 0, stream,
                           P.g[1].rowstart, P.g[1].rowend, P.g[1].ecol,
                           P.g[1].scale, B_, accI, out_IL_b);
    } else {
        // ============ Layout B: round-8 shared regions, 17 launches ============
        const int NROWPAD = 90004;
        const int EPMAX = 547 * 6144;
        ushort* fb16 = (ushort*)d_ws;
        float* accI  = (float*)(fb16 + (size_t)90001 * D + 32);
        float* scB   = accI + (size_t)I_ * D;
        int* epB     = (int*)(scB + NROWPAD);
        ushort* gb16 = (ushort*)epB;
        int* ecolB   = epB + EPMAX;
        int* rsB     = ecolB + EPMAX;
        int* reB     = rsB + NROWPAD;
        int* bkB     = reB + NROWPAD;
        int* cntB    = epB + 2950000;

        for (int i = 0; i < 4; i++) {
            GD& d = P.g[i];
            d.rows = rowsArr[i]; d.cols = rowsArr[i] + nnzArr[i];
            d.ep = epB; d.cnt = cntB + coArr[i]; d.bktcur = bkB + i * MAXB;
            d.ecol = ecolB; d.rowstart = rsB; d.rowend = reB; d.scale = scB;
            d.rawA = users; d.rawB_adj = rawBArr[i];
            d.fb = fb16;
            d.nnz = nnzArr[i]; d.G = GArr[i]; d.nbuck = nbArr[i]; d.seg = i;
            d.n = nArr[i]; d.mode = modeArr[i]; d.do_pad = padArr[i]; d.do_stage = stgArr[i];
        }
        hipLaunchKernelGGL(k_cntB,  dim3(P.Gpre[4]),  dim3(256), 0, stream, P);
        hipLaunchKernelGGL(k_scanB, dim3(P.nbpre[4]), dim3(256), 0, stream, P);

        auto one = [&](int i) {                    // single-graph scat+sort
            GB4 Q{};
            Q.ng = 1; Q.g[0] = P.g[i];
            Q.Gpre[0] = 0; Q.Gpre[1] = GArr[i];
            Q.nbpre[0] = 0; Q.nbpre[1] = nbArr[i];
            hipLaunchKernelGGL(k_scatB, dim3(GArr[i]),  dim3(256), 0, stream, Q);
            hipLaunchKernelGGL(k_sortB, dim3(nbArr[i]), dim3(256), 0, stream, Q);
        };
        auto layers = [&](int i, float* accA, float* accB) {
            LB3 L{};
            L.nl = 1; L.qpre[0] = 0; L.qpre[1] = (nArr[i] + 15) >> 4;
            LD& l = L.l[0];
            l.rowstart = rsB; l.rowend = reB; l.scale = scB; l.ecol = ecolB;
            l.rawA = users; l.rawB_adj = rawBArr[i];
            l.accA = accA; l.accB = accB; l.n = nArr[i];
            l.x = fb16; l.fout = gb16; l.inv = 0.5f; l.write_f = 1; l.init = 1;
            hipLaunchKernelGGL(k_layerB, dim3(L.qpre[1]), dim3(256), 0, stream, L);
            l.x = gb16; l.fout = (ushort*)nullptr; l.inv = 1.0f / 3.0f;
            l.write_f = 0; l.init = 0;
            hipLaunchKernelGGL(k_layerB, dim3(L.qpre[1]), dim3(256), 0, stream, L);
        };

        one(0); layers(0, out_IL_u, accI);
        one(1);
        hipLaunchKernelGGL(k_spmm_csr, dim3((B_ + 3) / 4), dim3(256), 0, stream,
                           rsB, reB, ecolB, scB, B_, accI, out_IL_b);
        one(2); layers(2, out_BL_u, out_BL_b);
        one(3); layers(3, out_XL_u, out_XL_b);
    }
}

// Round 11
// 422.867 us; speedup vs baseline: 4.1313x; 1.0199x over previous
//
#include <hip/hip_runtime.h>

#define D 64
constexpr int U_ = 50000, B_ = 20000, I_ = 40000;
constexpr int RPB  = 128;
constexpr int MAXB = 708;
constexpr int PTILE = 8192;

// Side-dependent bucket capacities (exact counts + x8 row padding + >=9 sigma).
constexpr int NBU = 390;
constexpr int CAPU_UI = 3584, CAPB_UI = 4352;   // deg 20 / 25 per row
constexpr int CAPA    = 2560;                   // agg: unpadded rows, deg 15
constexpr int CAPU_UB = 2432, CAPB_UB = 4864;   // deg 12 / 30
constexpr int CAPU_UX = 2944, CAPB_UX = 6272;   // deg 16 / 40
// per-graph ep/ecol extents
constexpr int EXT_UI = NBU * CAPU_UI + 314 * CAPB_UI;  // 2,764,288
constexpr int EXT_AG = 157 * CAPA;                     //   401,920
constexpr int EXT_UB = NBU * CAPU_UB + 157 * CAPB_UB;  // 1,712,128
constexpr int EXT_UX = NBU * CAPU_UX + 157 * CAPB_UX;  // 2,132,864
constexpr long long EXT_SUM = (long long)EXT_UI + EXT_AG + EXT_UB + EXT_UX; // 7,011,200

__device__ __forceinline__ int g_nbU(int seg) { return seg == 1 ? 0 : NBU; }
__device__ __forceinline__ int g_capU(int seg) {
    switch (seg) { case 0: return CAPU_UI; case 1: return CAPA;
                   case 2: return CAPU_UB; default: return CAPU_UX; }
}
__device__ __forceinline__ int g_capB(int seg) {
    switch (seg) { case 0: return CAPB_UI; case 1: return CAPA;
                   case 2: return CAPB_UB; default: return CAPB_UX; }
}
__device__ __forceinline__ int bbase(int seg, int b) {   // graph-local region start
    int nbU = g_nbU(seg);
    return (b <= nbU) ? b * g_capU(seg)
                      : nbU * g_capU(seg) + (b - nbU) * g_capB(seg);
}

__device__ __forceinline__ unsigned short f2bf(float f) {   // RTN-even
    unsigned int u = __float_as_uint(f);
    return (unsigned short)((u + 0x7FFFu + ((u >> 16) & 1u)) >> 16);
}

struct GD {                       // per-graph build descriptor (graph-local bases)
    const int* rows; const int* cols;
    int* ep; int* cnt; int* bktcur;
    int* ecol; int* rowstart; int* rowend; float* scale;
    const float* rawA; const float* rawB_adj;
    ushort* fb;
    int nnz, G, nbuck, seg, n, mode, do_pad, do_stage;
};
struct GB4 { GD g[4]; int ng; int Gpre[5]; int nbpre[5]; };

// ---- batched cnt: per-(block,bucket) histogram -> cnt[b*G + rel] ----
__global__ void __launch_bounds__(256) k_cntB(GB4 P) {
    __shared__ int lcnt[MAXB];
    int blk = blockIdx.x, t = threadIdx.x;
    int gi = 0;
    while (gi + 1 < P.ng && blk >= P.Gpre[gi + 1]) gi++;
    const GD& d = P.g[gi];
    int rel = blk - P.Gpre[gi];
    const int* __restrict__ rows = d.rows;
    for (int i = t; i < d.nbuck; i += 256) lcnt[i] = 0;
    __syncthreads();
    int e0 = rel * PTILE, e1 = min(e0 + PTILE, d.nnz);
    int e = e0 + t;
    for (; e + 1792 < e1; e += 2048) {             // 8-way ILP
        int r[8];
        #pragma unroll
        for (int k = 0; k < 8; k++) r[k] = rows[e + k * 256];
        #pragma unroll
        for (int k = 0; k < 8; k++) atomicAdd(&lcnt[r[k] >> 7], 1);
    }
    for (; e < e1; e += 256) atomicAdd(&lcnt[rows[e] >> 7], 1);
    __syncthreads();
    for (int b = t; b < d.nbuck; b += 256) d.cnt[(size_t)b * d.G + rel] = lcnt[b];
}

// ---- batched scan: per-bucket exclusive prefix over blocks (G <= 256) ----
__global__ void __launch_bounds__(256) k_scanB(GB4 P) {
    __shared__ int sv[256];
    int bk = blockIdx.x, t = threadIdx.x;
    int gi = 0;
    while (gi + 1 < P.ng && bk >= P.nbpre[gi + 1]) gi++;
    const GD& d = P.g[gi];
    int rel = bk - P.nbpre[gi];
    int x = (t < d.G) ? d.cnt[(size_t)rel * d.G + t] : 0;
    sv[t] = x;
    __syncthreads();
    for (int off = 1; off < 256; off <<= 1) {      // Hillis-Steele inclusive
        int y = (t >= off) ? sv[t - off] : 0;
        __syncthreads();
        sv[t] += y;
        __syncthreads();
    }
    int bb = bbase(d.seg, rel);
    if (t < d.G) d.cnt[(size_t)rel * d.G + t] = bb + sv[t] - x;   // exclusive base
    if (t == 255) d.bktcur[rel] = bb + sv[255];                   // bucket end
}

// ---- batched scatter: edges to exact graph-local positions (packed 4B) ----
__global__ void __launch_bounds__(256) k_scatB(GB4 P) {
    __shared__ int lbase[MAXB], lcnt[MAXB], llim[MAXB];
    int blk = blockIdx.x, t = threadIdx.x;
    int gi = 0;
    while (gi + 1 < P.ng && blk >= P.Gpre[gi + 1]) gi++;
    const GD& d = P.g[gi];
    int rel = blk - P.Gpre[gi];
    const int* __restrict__ rows = d.rows;
    const int* __restrict__ cols = d.cols;
    int* __restrict__ ep = d.ep;
    for (int b = t; b < d.nbuck; b += 256) {
        lbase[b] = d.cnt[(size_t)b * d.G + rel];
        llim[b]  = bbase(d.seg, b + 1);
        lcnt[b]  = 0;
    }
    __syncthreads();
    int e0 = rel * PTILE, e1 = min(e0 + PTILE, d.nnz);
    int e = e0 + t;
    for (; e + 1792 < e1; e += 2048) {             // 8-way ILP
        int r[8], c[8];
        #pragma unroll
        for (int k = 0; k < 8; k++) { r[k] = rows[e + k * 256]; c[k] = cols[e + k * 256]; }
        #pragma unroll
        for (int k = 0; k < 8; k++) {
            int b = r[k] >> 7;
            int pos = lbase[b] + atomicAdd(&lcnt[b], 1);
            if (pos < llim[b])                     // overflow guard (>=9 sigma)
                ep[pos] = ((r[k] & (RPB - 1)) << 17) | c[k];
        }
    }
    for (; e < e1; e += 256) {
        int r = rows[e], c = cols[e];
        int b = r >> 7;
        int pos = lbase[b] + atomicAdd(&lcnt[b], 1);
        if (pos < llim[b])
            ep[pos] = ((r & (RPB - 1)) << 17) | c;
    }
}

// ---- batched counting sort -> padded CSR + scale + fused bf16 stage ----
__global__ void __launch_bounds__(256) k_sortB(GB4 P) {
    __shared__ int lc[4 * 129];                    // 4 replicas, stride 129
    __shared__ float sscale[RPB];
    __shared__ int wtot;
    int bk = blockIdx.x, t = threadIdx.x;
    int gi = 0;
    while (gi + 1 < P.ng && bk >= P.nbpre[gi + 1]) gi++;
    const GD& d = P.g[gi];
    int b = bk - P.nbpre[gi];
    const int* __restrict__ ep = d.ep;
    int* __restrict__ ecol = d.ecol;
    int s = bbase(d.seg, b);
    int e = min(d.bktcur[b], bbase(d.seg, b + 1));
    int ne = e - s;
    for (int i = t; i < 4 * 129; i += 256) lc[i] = 0;
    __syncthreads();
    int rep = (t & 3) * 129;
    int i = t;
    for (; i + 768 < ne; i += 1024) {              // 4-way ILP histogram
        int p0 = ep[s+i], p1 = ep[s+i+256], p2 = ep[s+i+512], p3 = ep[s+i+768];
        atomicAdd(&lc[rep + (p0 >> 17)], 1); atomicAdd(&lc[rep + (p1 >> 17)], 1);
        atomicAdd(&lc[rep + (p2 >> 17)], 1); atomicAdd(&lc[rep + (p3 >> 17)], 1);
    }
    for (; i < ne; i += 256) { int p = ep[s + i]; atomicAdd(&lc[rep + (p >> 17)], 1); }
    __syncthreads();
    int c_t = 0, pc_t = 0, v = 0;
    if (t < RPB) {                                 // waves 0,1: counts + wave scan
        c_t = lc[t] + lc[129 + t] + lc[258 + t] + lc[387 + t];
        pc_t = d.do_pad ? ((c_t + 7) & ~7) : c_t;
        v = pc_t;
        for (int off = 1; off < 64; off <<= 1) {
            int y = __shfl_up(v, off, 64);
            if ((t & 63) >= off) v += y;
        }
    }
    if (t == 63) wtot = v;
    __syncthreads();
    if (t >= 64 && t < RPB) v += wtot;             // wave 1 adds wave 0 total
    if (t < RPB) {
        int row = b * RPB + t;
        if (row < d.n) {
            int st = s + (v - pc_t);               // exclusive prefix
            d.rowstart[row] = st;
            d.rowend[row]   = st + pc_t;           // PADDED end
            float sc = (d.mode == 0) ? 1.0f / (sqrtf((float)c_t) + 1e-8f)
                                     : 1.0f / (float)max(c_t, 1);
            d.scale[row] = sc;
            sscale[t] = sc;
            for (int k = c_t; k < pc_t; k++) ecol[st + k] = d.n;  // pad -> zero row
            lc[t] = st;                            // replica 0 becomes write cursor
        } else lc[t] = 0;
    }
    __syncthreads();
    i = t;
    for (; i + 768 < ne; i += 1024) {              // 4-way ILP placement
        int p0 = ep[s+i], p1 = ep[s+i+256], p2 = ep[s+i+512], p3 = ep[s+i+768];
        int q0 = atomicAdd(&lc[p0 >> 17], 1); ecol[q0] = p0 & 0x1FFFF;
        int q1 = atomicAdd(&lc[p1 >> 17], 1); ecol[q1] = p1 & 0x1FFFF;
        int q2 = atomicAdd(&lc[p2 >> 17], 1); ecol[q2] = p2 & 0x1FFFF;
        int q3 = atomicAdd(&lc[p3 >> 17], 1); ecol[q3] = p3 & 0x1FFFF;
    }
    for (; i < ne; i += 256) {
        int p = ep[s + i];
        int q = atomicAdd(&lc[p >> 17], 1);
        ecol[q] = p & 0x1FFFF;
    }
    if (d.do_stage) {                              // fused premultiplied bf16 stage
        int r0 = b * RPB;
        for (int idx = t; idx < RPB * 16; idx += 256) {
            int rl = idx >> 4, q = idx & 15;
            int row = r0 + rl;
            if (row > d.n) continue;
            ushort4 o;
            if (row == d.n) {
                o = make_ushort4(0, 0, 0, 0);      // zero redirect row
            } else {
                float sc = sscale[rl];
                float4 vv = (row < U_) ? ((const float4*)d.rawA)[(size_t)row * 16 + q]
                                       : ((const float4*)d.rawB_adj)[(size_t)row * 16 + q];
                o.x = f2bf(vv.x * sc); o.y = f2bf(vv.y * sc);
                o.z = f2bf(vv.z * sc); o.w = f2bf(vv.w * sc);
            }
            ((ushort4*)d.fb)[(size_t)row * 16 + q] = o;
        }
    }
}

struct LD {                       // per-graph layer descriptor
    const int* rowstart; const int* rowend; const float* scale;
    const int* ecol; const ushort* x; ushort* fout;
    const float* rawA; const float* rawB_adj;
    float* accA; float* accB; float* l2s;
    float inv; int n, phase;      // phase 0: write gb+l2s, no acc. phase 1: final acc.
};
struct LB3 { LD l[3]; int nl; int qpre[4]; };

// ---- batched fused CSR-SpMM + scale + l2norm (4 rows/wave) ----
// phase 0: y0; gb = bf16(s*y0); l2s = rn0/s  (acc untouched -> saves 59 MB write)
// phase 1: y1; acc = raw + gb_own*l2s + y1*rn1  (single acc write)
__global__ void __launch_bounds__(256) k_layerB(LB3 P) {
    int blk = blockIdx.x;
    int gi = 0;
    while (gi + 1 < P.nl && blk >= P.qpre[gi + 1]) gi++;
    const LD& d = P.l[gi];
    int rel = blk - P.qpre[gi];
    if (d.phase == 0 && rel == 0 && threadIdx.x < 16)   // zero redirect row of gb
        ((ushort4*)(d.fout + ((size_t)d.n << 6)))[threadIdx.x] = make_ushort4(0, 0, 0, 0);
    const int* __restrict__ rowstart = d.rowstart;
    const int* __restrict__ rowend   = d.rowend;
    const int* __restrict__ ecol     = d.ecol;
    const float* __restrict__ scale  = d.scale;
    const uint4* __restrict__ xb = (const uint4*)d.x;   // row r, chunk q at r*8+q
    const int lane = threadIdx.x & 63;
    const int qtr  = lane >> 4;
    const int ql   = lane & 15;
    const int g = ql >> 3, q = ql & 7;
    int rowA = (rel << 4) + ((threadIdx.x >> 6) << 2);
    if (rowA >= d.n) return;
    int row = rowA + qtr;
    int s = 0, e = 0;
    if (row < d.n) { s = rowstart[row]; e = rowend[row]; }
    float a0=0.f,a1=0.f,a2=0.f,a3=0.f,a4=0.f,a5=0.f,a6=0.f,a7=0.f;
#define LDQ(m, vv) { int c_ = __shfl(cj, (qtr << 4) + ((m) << 1) + g, 64); \
                     vv = xb[((size_t)(unsigned)c_ << 3) + (unsigned)q]; }
#define ACCQ(vv) { \
    a0 += __uint_as_float(vv.x << 16); a1 += __uint_as_float(vv.x & 0xFFFF0000u); \
    a2 += __uint_as_float(vv.y << 16); a3 += __uint_as_float(vv.y & 0xFFFF0000u); \
    a4 += __uint_as_float(vv.z << 16); a5 += __uint_as_float(vv.z & 0xFFFF0000u); \
    a6 += __uint_as_float(vv.w << 16); a7 += __uint_as_float(vv.w & 0xFFFF0000u); }
    for (int base = s; base < e; base += 16) {
        int jn = e - base;                        // 8 or 16 (x8-padded rows)
        int cj = ecol[base + ql];
        uint4 v0, v1, v2, v3, v4, v5, v6, v7;
        if (jn >= 16) {
            LDQ(0, v0); LDQ(1, v1); LDQ(2, v2); LDQ(3, v3);
            LDQ(4, v4); ACCQ(v0);
            LDQ(5, v5); ACCQ(v1);
            LDQ(6, v6); ACCQ(v2);
            LDQ(7, v7); ACCQ(v3);
            ACCQ(v4); ACCQ(v5); ACCQ(v6); ACCQ(v7);
        } else {
            LDQ(0, v0); LDQ(1, v1); LDQ(2, v2); LDQ(3, v3);
            ACCQ(v0); ACCQ(v1); ACCQ(v2); ACCQ(v3);
        }
    }
#undef LDQ
#undef ACCQ
#define RED(aa) { aa += __shfl_xor(aa, 8, 64); }
    RED(a0) RED(a1) RED(a2) RED(a3) RED(a4) RED(a5) RED(a6) RED(a7)
#undef RED
    float srow = (row < d.n) ? scale[row] : 1.f;
    float mlt = srow * d.inv;
    float w0=a0*mlt, w1=a1*mlt, w2=a2*mlt, w3=a3*mlt;
    float w4=a4*mlt, w5=a5*mlt, w6=a6*mlt, w7=a7*mlt;
    float sq = w0*w0 + w1*w1 + w2*w2 + w3*w3 + w4*w4 + w5*w5 + w6*w6 + w7*w7;
    sq += __shfl_xor(sq, 1, 64); sq += __shfl_xor(sq, 2, 64); sq += __shfl_xor(sq, 4, 64);
    float rn = 1.0f / fmaxf(sqrtf(sq), 1e-12f);
    if (row < d.n && g == 0) {                     // 8 lanes per quarter own the row
        size_t o = ((size_t)row << 6) + ((unsigned)q << 3);
        if (d.phase == 0) {                        // premult bf16 for next layer
            unsigned p0 = (unsigned)f2bf(w0*srow) | ((unsigned)f2bf(w1*srow) << 16);
            unsigned p1 = (unsigned)f2bf(w2*srow) | ((unsigned)f2bf(w3*srow) << 16);
            unsigned p2 = (unsigned)f2bf(w4*srow) | ((unsigned)f2bf(w5*srow) << 16);
            unsigned p3 = (unsigned)f2bf(w6*srow) | ((unsigned)f2bf(w7*srow) << 16);
            *(uint4*)(d.fout + o) = make_uint4(p0, p1, p2, p3);
            if (q == 0) d.l2s[row] = rn / srow;    // l2norm(y0) = gb * l2s
        } else {                                   // final: raw + gb*l2s + y1*rn
            uint4 gv = *(const uint4*)(d.x + o);   // own gb chunk (x IS gb)
            float lv = d.l2s[row];
            float g0 = __uint_as_float(gv.x << 16) * lv,
                  g1 = __uint_as_float(gv.x & 0xFFFF0000u) * lv,
                  g2 = __uint_as_float(gv.y << 16) * lv,
                  g3 = __uint_as_float(gv.y & 0xFFFF0000u) * lv,
                  g4 = __uint_as_float(gv.z << 16) * lv,
                  g5 = __uint_as_float(gv.z & 0xFFFF0000u) * lv,
                  g6 = __uint_as_float(gv.w << 16) * lv,
                  g7 = __uint_as_float(gv.w & 0xFFFF0000u) * lv;
            const float4* rp = (const float4*)((row < U_) ? d.rawA : d.rawB_adj)
                               + ((size_t)row << 4) + ((unsigned)q << 1);
            float4 c0 = rp[0], c1 = rp[1];
            float* p = (row < U_) ? d.accA + o : d.accB + (o - ((size_t)U_ << 6));
            ((float4*)p)[0] = make_float4(c0.x + g0 + w0*rn, c0.y + g1 + w1*rn,
                                          c0.z + g2 + w2*rn, c0.w + g3 + w3*rn);
            ((float4*)p)[1] = make_float4(c1.x + g4 + w4*rn, c1.y + g5 + w5*rn,
                                          c1.z + g6 + w6*rn, c1.w + g7 + w7*rn);
        }
    }
}

// fp32 CSR-SpMM, 4 rows/wave, float4 chunks (16 lanes x 16B = full 256B row/edge)
__global__ void __launch_bounds__(256)
k_spmm4(const int* __restrict__ rowstart, const int* __restrict__ rowend,
        const int* __restrict__ ecol, const float* __restrict__ rs, int n,
        const float* __restrict__ x, float* __restrict__ y) {
    const int lane = threadIdx.x & 63;
    const int qtr = lane >> 4, ql = lane & 15;
    int rowA = (blockIdx.x << 4) + ((threadIdx.x >> 6) << 2);
    if (rowA >= n) return;
    int row = rowA + qtr;
    bool live = row < n;
    int s = live ? rowstart[row] : 0, e = live ? rowend[row] : 0;
    const float4* __restrict__ xb = (const float4*)x;
    float4 acc = make_float4(0.f, 0.f, 0.f, 0.f);
    for (int base = s; base < e; base += 16) {
        int jn = e - base; if (jn > 16) jn = 16;
        int li = base + (ql < jn ? ql : jn - 1);
        int cj = ecol[li];
        int j = 0;
        for (; j + 4 <= jn; j += 4) {              // 4-deep gather pipeline
            int c0 = __shfl(cj, (qtr << 4) + j + 0, 64);
            int c1 = __shfl(cj, (qtr << 4) + j + 1, 64);
            int c2 = __shfl(cj, (qtr << 4) + j + 2, 64);
            int c3 = __shfl(cj, (qtr << 4) + j + 3, 64);
            float4 v0 = xb[(size_t)c0 * 16 + ql];
            float4 v1 = xb[(size_t)c1 * 16 + ql];
            float4 v2 = xb[(size_t)c2 * 16 + ql];
            float4 v3 = xb[(size_t)c3 * 16 + ql];
            acc.x += (v0.x + v1.x) + (v2.x + v3.x);
            acc.y += (v0.y + v1.y) + (v2.y + v3.y);
            acc.z += (v0.z + v1.z) + (v2.z + v3.z);
            acc.w += (v0.w + v1.w) + (v2.w + v3.w);
        }
        for (; j < jn; j++) {
            int c = __shfl(cj, (qtr << 4) + j, 64);
            float4 v = xb[(size_t)c * 16 + ql];
            acc.x += v.x; acc.y += v.y; acc.z += v.z; acc.w += v.w;
        }
    }
    if (live) {
        float sc = rs[row];
        ((float4*)y)[(size_t)row * 16 + ql] =
            make_float4(acc.x * sc, acc.y * sc, acc.z * sc, acc.w * sc);
    }
}

extern "C" void kernel_launch(void* const* d_in, const int* in_sizes, int n_in,
                              void* d_out, int out_size, void* d_ws, size_t ws_size,
                              hipStream_t stream) {
    const float* users   = (const float*)d_in[0];
    const float* bundles = (const float*)d_in[1];
    const float* items   = (const float*)d_in[2];
    const int*   ui_idx  = (const int*)d_in[3];
    const int*   ub_idx  = (const int*)d_in[5];
    const int*   ubx_idx = (const int*)d_in[7];
    const int*   agg_idx = (const int*)d_in[9];
    const int ui_nnz  = in_sizes[4];
    const int ub_nnz  = in_sizes[6];
    const int ubx_nnz = in_sizes[8];
    const int agg_nnz = in_sizes[10];

    float* out = (float*)d_out;
    const size_t rowf = (size_t)D;
    float* out_IL_u = out;
    float* out_BL_u = out + (size_t)U_ * rowf;
    float* out_XL_u = out + (size_t)2 * U_ * rowf;
    float* out_IL_b = out + (size_t)3 * U_ * rowf;
    float* out_BL_b = out + (size_t)3 * U_ * rowf + (size_t)B_ * rowf;
    float* out_XL_b = out + (size_t)3 * U_ * rowf + (size_t)2 * B_ * rowf;

    const int G0 = (ui_nnz  + PTILE - 1) / PTILE;
    const int G1 = (agg_nnz + PTILE - 1) / PTILE;
    const int G2 = (ub_nnz  + PTILE - 1) / PTILE;
    const int G3 = (ubx_nnz + PTILE - 1) / PTILE;
    const int NB0 = 704, NB1 = 157, NB2 = 547, NB3 = 547;
    const size_t co0 = 0, co1 = (size_t)NB0 * G0, co2 = co1 + (size_t)NB1 * G1,
                 co3 = co2 + (size_t)NB2 * G2, cntInts = co3 + (size_t)NB3 * G3;
    const int nU = U_ + I_, nB2g = U_ + B_;        // 90000, 70000

    const int* rowsArr[4] = { ui_idx, agg_idx, ub_idx, ubx_idx };
    const int nnzArr[4]   = { ui_nnz, agg_nnz, ub_nnz, ubx_nnz };
    const int GArr[4]     = { G0, G1, G2, G3 };
    const int nbArr[4]    = { NB0, NB1, NB2, NB3 };
    const int nArr[4]     = { nU, B_, nB2g, nB2g };
    const int modeArr[4]  = { 0, 1, 0, 0 };
    const int padArr[4]   = { 1, 0, 1, 1 };
    const int stgArr[4]   = { 1, 0, 1, 1 };
    const size_t coArr[4] = { co0, co1, co2, co3 };
    const float* rawBArr[4] = { items - (size_t)U_ * rowf, users,
                                bundles - (size_t)U_ * rowf, bundles - (size_t)U_ * rowf };

    // ---- Layout A requirement (bytes) ----
    const size_t fbBytes  = 230003ull * 128;       // ui 90001 + ub 70001 + ubx 70001 rows
    const size_t accBytes = 40001ull * 256;
    const size_t ecBytes  = (size_t)EXT_SUM * 4;
    const size_t rsBytes  = 250016ull * 4;         // 90004+20004+70004+70004
    const size_t bkBytes  = 4ull * MAXB * 4;
    const size_t epcnt    = (size_t)EXT_SUM * 4 + cntInts * 4;
    const size_t tailB    = epcnt > fbBytes ? epcnt : fbBytes;   // gb aliases ep+cnt
    const size_t reqA     = fbBytes + accBytes + ecBytes + 4 * rsBytes + bkBytes + tailB + 4096;

    GB4 P{};
    P.ng = 4;
    P.Gpre[0] = 0; P.nbpre[0] = 0;
    for (int i = 0; i < 4; i++) { P.Gpre[i+1] = P.Gpre[i] + GArr[i]; P.nbpre[i+1] = P.nbpre[i] + nbArr[i]; }

    if (ws_size >= reqA) {
        // ================= Layout A: disjoint regions, 7 launches =================
        char* w = (char*)d_ws;
        ushort* fbA   = (ushort*)w;                 w += fbBytes;
        float* accI   = (float*)w;                  w += accBytes;
        int*   ecolA  = (int*)w;                    w += ecBytes;
        int*   rsA    = (int*)w;                    w += rsBytes;
        int*   reA    = (int*)w;                    w += rsBytes;
        float* scA    = (float*)w;                  w += rsBytes;
        float* l2sA   = (float*)w;                  w += rsBytes;
        int*   bkA    = (int*)w;                    w += bkBytes;
        int*   epA    = (int*)w;                    /* ep then cnt */
        int*   cntA   = epA + EXT_SUM;
        ushort* gbA   = (ushort*)epA;               // aliases ep+cnt (dead after sort4)

        const size_t epoff[4] = { 0, (size_t)EXT_UI, (size_t)EXT_UI + EXT_AG,
                                  (size_t)EXT_UI + EXT_AG + EXT_UB };
        const size_t roff[4]  = { 0, 90004, 110008, 180012 };
        const size_t fboff[4] = { 0, 0, 90001ull * 64, 160002ull * 64 };  // agg unused

        for (int i = 0; i < 4; i++) {
            GD& d = P.g[i];
            d.rows = rowsArr[i]; d.cols = rowsArr[i] + nnzArr[i];
            d.ep = epA + epoff[i]; d.cnt = cntA + coArr[i]; d.bktcur = bkA + i * MAXB;
            d.ecol = ecolA + epoff[i];
            d.rowstart = rsA + roff[i]; d.rowend = reA + roff[i]; d.scale = scA + roff[i];
            d.rawA = users; d.rawB_adj = rawBArr[i];
            d.fb = (i == 1) ? nullptr : fbA + fboff[i];
            d.nnz = nnzArr[i]; d.G = GArr[i]; d.nbuck = nbArr[i]; d.seg = i;
            d.n = nArr[i]; d.mode = modeArr[i]; d.do_pad = padArr[i]; d.do_stage = stgArr[i];
        }
        hipLaunchKernelGGL(k_cntB,  dim3(P.Gpre[4]),  dim3(256), 0, stream, P);
        hipLaunchKernelGGL(k_scanB, dim3(P.nbpre[4]), dim3(256), 0, stream, P);
        hipLaunchKernelGGL(k_scatB, dim3(P.Gpre[4]),  dim3(256), 0, stream, P);
        hipLaunchKernelGGL(k_sortB, dim3(P.nbpre[4]), dim3(256), 0, stream, P);

        float* accAArr[3] = { out_IL_u, out_BL_u, out_XL_u };
        float* accBArr[3] = { accI, out_BL_b, out_XL_b };
        int gsel[3] = { 0, 2, 3 };
        LB3 L{};
        L.nl = 3; L.qpre[0] = 0;
        for (int j = 0; j < 3; j++) {
            int i = gsel[j];
            LD& l = L.l[j];
            l.rowstart = P.g[i].rowstart; l.rowend = P.g[i].rowend; l.scale = P.g[i].scale;
            l.ecol = P.g[i].ecol; l.rawA = users; l.rawB_adj = rawBArr[i];
            l.accA = accAArr[j]; l.accB = accBArr[j];
            l.l2s = l2sA + roff[i];
            l.n = nArr[i];
            L.qpre[j + 1] = L.qpre[j] + ((nArr[i] + 15) >> 4);
        }
        // layer 0 (phase 0): gb + l2s only
        for (int j = 0; j < 3; j++) {
            int i = gsel[j];
            L.l[j].x = fbA + fboff[i]; L.l[j].fout = gbA + fboff[i];
            L.l[j].inv = 0.5f; L.l[j].phase = 0;
        }
        hipLaunchKernelGGL(k_layerB, dim3(L.qpre[3]), dim3(256), 0, stream, L);
        // layer 1 (phase 1): acc = raw + gb*l2s + l2norm(y1)
        for (int j = 0; j < 3; j++) {
            int i = gsel[j];
            L.l[j].x = gbA + fboff[i]; L.l[j].fout = (ushort*)nullptr;
            L.l[j].inv = 1.0f / 3.0f; L.l[j].phase = 1;
        }
        hipLaunchKernelGGL(k_layerB, dim3(L.qpre[3]), dim3(256), 0, stream, L);
        // bundle aggregation: IL_b = agg @ acc_itm
        hipLaunchKernelGGL(k_spmm4, dim3((B_ + 15) / 16), dim3(256), 0, stream,
                           P.g[1].rowstart, P.g[1].rowend, P.g[1].ecol,
                           P.g[1].scale, B_, accI, out_IL_b);
    } else {
        // ============ Layout B: shared regions, serialized graphs ============
        const int NROWPAD = 90004;
        const int EPMAX = 547 * 6144;
        ushort* fb16 = (ushort*)d_ws;
        float* accI  = (float*)(fb16 + (size_t)90001 * D + 32);
        float* scB   = accI + (size_t)I_ * D;
        int* epB     = (int*)(scB + NROWPAD);
        ushort* gb16 = (ushort*)epB;
        int* ecolB   = epB + EPMAX;
        int* rsB     = ecolB + EPMAX;
        int* reB     = rsB + NROWPAD;
        int* bkB     = reB + NROWPAD;
        float* l2sB  = (float*)(bkB + 4 * MAXB);
        int* cntB    = epB + 2950000;

        for (int i = 0; i < 4; i++) {
            GD& d = P.g[i];
            d.rows = rowsArr[i]; d.cols = rowsArr[i] + nnzArr[i];
            d.ep = epB; d.cnt = cntB + coArr[i]; d.bktcur = bkB + i * MAXB;
            d.ecol = ecolB; d.rowstart = rsB; d.rowend = reB; d.scale = scB;
            d.rawA = users; d.rawB_adj = rawBArr[i];
            d.fb = fb16;
            d.nnz = nnzArr[i]; d.G = GArr[i]; d.nbuck = nbArr[i]; d.seg = i;
            d.n = nArr[i]; d.mode = modeArr[i]; d.do_pad = padArr[i]; d.do_stage = stgArr[i];
        }
        hipLaunchKernelGGL(k_cntB,  dim3(P.Gpre[4]),  dim3(256), 0, stream, P);
        hipLaunchKernelGGL(k_scanB, dim3(P.nbpre[4]), dim3(256), 0, stream, P);

        auto one = [&](int i) {                    // single-graph scat+sort
            GB4 Q{};
            Q.ng = 1; Q.g[0] = P.g[i];
            Q.Gpre[0] = 0; Q.Gpre[1] = GArr[i];
            Q.nbpre[0] = 0; Q.nbpre[1] = nbArr[i];
            hipLaunchKernelGGL(k_scatB, dim3(GArr[i]),  dim3(256), 0, stream, Q);
            hipLaunchKernelGGL(k_sortB, dim3(nbArr[i]), dim3(256), 0, stream, Q);
        };
        auto layers = [&](int i, float* accA, float* accB) {
            LB3 L{};
            L.nl = 1; L.qpre[0] = 0; L.qpre[1] = (nArr[i] + 15) >> 4;
            LD& l = L.l[0];
            l.rowstart = rsB; l.rowend = reB; l.scale = scB; l.ecol = ecolB;
            l.rawA = users; l.rawB_adj = rawBArr[i];
            l.accA = accA; l.accB = accB; l.l2s = l2sB; l.n = nArr[i];
            l.x = fb16; l.fout = gb16; l.inv = 0.5f; l.phase = 0;
            hipLaunchKernelGGL(k_layerB, dim3(L.qpre[1]), dim3(256), 0, stream, L);
            l.x = gb16; l.fout = (ushort*)nullptr; l.inv = 1.0f / 3.0f; l.phase = 1;
            hipLaunchKernelGGL(k_layerB, dim3(L.qpre[1]), dim3(256), 0, stream, L);
        };

        one(0); layers(0, out_IL_u, accI);
        one(1);
        hipLaunchKernelGGL(k_spmm4, dim3((B_ + 15) / 16), dim3(256), 0, stream,
                           rsB, reB, ecolB, scB, B_, accI, out_IL_b);
        one(2); layers(2, out_BL_u, out_BL_b);
        one(3); layers(3, out_XL_u, out_XL_b);
    }
}